// Round 1
// baseline (622.296 us; speedup 1.0000x reference)
//
#include <hip/hip_runtime.h>
#include <hip/hip_bf16.h>

typedef unsigned short u16;
typedef float f32x4 __attribute__((ext_vector_type(4)));
typedef __bf16 bf16x8 __attribute__((ext_vector_type(8)));

#define DEVI static __device__ __forceinline__

static constexpr float QK_SCALE = 0.125f * 1.44269504088896340736f; // 1/sqrt(64) * log2(e)

DEVI u16 bfbits(float f) { __bf16 h = (__bf16)f; return __builtin_bit_cast(u16, h); }

typedef unsigned int uint_g __attribute__((address_space(1)));
typedef unsigned int uint_l __attribute__((address_space(3)));

DEVI void gl_lds16(const void* g, void* l) {
  __builtin_amdgcn_global_load_lds((const uint_g*)g, (uint_l*)l, 16, 0, 0);
}

// ---------------- f32 -> bf16 convert (vectorized) ----------------
__global__ __launch_bounds__(256) void cvt_f32_bf16(const float* __restrict__ x,
                                                    u16* __restrict__ y, int n4) {
  int i = blockIdx.x * blockDim.x + threadIdx.x;
  int stride = gridDim.x * blockDim.x;
  for (; i < n4; i += stride) {
    float4 v = ((const float4*)x)[i];
    ushort4 o;
    o.x = bfbits(v.x); o.y = bfbits(v.y); o.z = bfbits(v.z); o.w = bfbits(v.w);
    ((ushort4*)y)[i] = o;
  }
}

// ---------------- weight transpose W[K][N] f32 -> WT[N][K] bf16 ----------------
__global__ __launch_bounds__(256) void wtrans(const float* __restrict__ W,
                                              u16* __restrict__ WT, int K, int N) {
  __shared__ float t[32][33];
  int k0 = blockIdx.x * 32, n0 = blockIdx.y * 32;
  int tx = threadIdx.x & 31, ty = threadIdx.x >> 5;
#pragma unroll
  for (int i = 0; i < 4; ++i)
    t[ty + i * 8][tx] = W[(size_t)(k0 + ty + i * 8) * N + n0 + tx];
  __syncthreads();
#pragma unroll
  for (int i = 0; i < 4; ++i)
    WT[(size_t)(n0 + ty + i * 8) * K + k0 + tx] = bfbits(t[tx][ty + i * 8]);
}

// ---------------- bf16 GEMM: C[M,N] = A[M,K] * BT[N,K]^T + bias ----------------
// EPI: 0 = f32 out; 1 = bf16 out; 2 = bf16 out * QK_SCALE; 3 = bf16 out transposed per-batch [b][n][s]
template <int BM, int BN, int WM, int WN, int EPI>
__global__ __launch_bounds__(256) void gemm_bt(const u16* __restrict__ A,
                                               const u16* __restrict__ BT,
                                               const float* __restrict__ bias,
                                               void* __restrict__ out,
                                               int M, int N, int K) {
  constexpr int WROWS = BM / WM, WCOLS = BN / WN;
  constexpr int RT = WROWS / 16, CT = WCOLS / 16;
  __shared__ u16 Alds[BM * 64];
  __shared__ u16 Blds[BN * 64];
  const int tid = threadIdx.x, wave = tid >> 6, lane = tid & 63;
  const int lr = lane & 15, lg = lane >> 4;
  const int wr = wave / WN, wc = wave % WN;
  const int m0 = blockIdx.y * BM, n0 = blockIdx.x * BN;

  f32x4 acc[RT][CT] = {};
  const int nkt = K >> 6;
  for (int kt = 0; kt < nkt; ++kt) {
    const int k0 = kt * 64;
    // stage A tile [BM][64] with inverse-swizzled source so swizzled reads are linear
#pragma unroll
    for (int j = 0; j < BM / 32; ++j) {
      int row = j * 32 + (tid >> 3);
      int cel = ((tid & 7) * 8) ^ ((row & 7) << 3);
      gl_lds16(A + (size_t)(m0 + row) * K + k0 + cel,
               (char*)Alds + (j * 256 + wave * 64) * 16);
    }
#pragma unroll
    for (int j = 0; j < BN / 32; ++j) {
      int row = j * 32 + (tid >> 3);
      int cel = ((tid & 7) * 8) ^ ((row & 7) << 3);
      gl_lds16(BT + (size_t)(n0 + row) * K + k0 + cel,
               (char*)Blds + (j * 256 + wave * 64) * 16);
    }
    __syncthreads();
#pragma unroll
    for (int ks = 0; ks < 2; ++ks) {
      bf16x8 af[RT], bfv[CT];
#pragma unroll
      for (int rt = 0; rt < RT; ++rt) {
        int r = wr * WROWS + rt * 16 + lr;
        af[rt] = *(const bf16x8*)&Alds[r * 64 + ((ks * 32 + lg * 8) ^ ((r & 7) << 3))];
      }
#pragma unroll
      for (int ct = 0; ct < CT; ++ct) {
        int r = wc * WCOLS + ct * 16 + lr;
        bfv[ct] = *(const bf16x8*)&Blds[r * 64 + ((ks * 32 + lg * 8) ^ ((r & 7) << 3))];
      }
#pragma unroll
      for (int rt = 0; rt < RT; ++rt)
#pragma unroll
        for (int ct = 0; ct < CT; ++ct)
          acc[rt][ct] = __builtin_amdgcn_mfma_f32_16x16x32_bf16(af[rt], bfv[ct], acc[rt][ct], 0, 0, 0);
    }
    __syncthreads();
  }
  // epilogue
#pragma unroll
  for (int ct = 0; ct < CT; ++ct) {
    int n = n0 + wc * WCOLS + ct * 16 + lr;
    float bv = bias[n];
#pragma unroll
    for (int rt = 0; rt < RT; ++rt) {
#pragma unroll
      for (int r = 0; r < 4; ++r) {
        int m = m0 + wr * WROWS + rt * 16 + lg * 4 + r;
        float v = acc[rt][ct][r] + bv;
        if constexpr (EPI == 0) {
          ((float*)out)[(size_t)m * N + n] = v;
        } else if constexpr (EPI == 1) {
          ((u16*)out)[(size_t)m * N + n] = bfbits(v);
        } else if constexpr (EPI == 2) {
          ((u16*)out)[(size_t)m * N + n] = bfbits(v * QK_SCALE);
        } else {  // transposed per-batch: [b][n][s], S=2048
          int bb = m >> 11, s2 = m & 2047;
          ((u16*)out)[((size_t)bb * 64 + n) * 2048 + s2] = bfbits(v);
        }
      }
    }
  }
}

// ---------------- fused MQA attention ----------------
// grid (S/256, H, B), block 256 (4 waves, 64 q-rows each)
// qh [B*S][1024] bf16 (pre-scaled by QK_SCALE), kh [B*S][64] bf16, vhT [B][64][S] bf16
__global__ __launch_bounds__(256) void attn(const u16* __restrict__ qh,
                                            const u16* __restrict__ kh,
                                            const u16* __restrict__ vhT,
                                            u16* __restrict__ att) {
  const int b = blockIdx.z, h = blockIdx.y;
  const int wave = threadIdx.x >> 6, lane = threadIdx.x & 63;
  const int lr = lane & 15, lg = lane >> 4;
  const int q0 = blockIdx.x * 256 + wave * 64;
  __shared__ u16 plds[4][64 * 64];
  u16* P = plds[wave];
  const u16* Qb = qh + (size_t)(b * 2048 + q0) * 1024 + h * 64;
  const u16* Kb = kh + (size_t)b * 2048 * 64;
  const u16* Vb = vhT + (size_t)b * 64 * 2048;

  bf16x8 qf[4][2];
#pragma unroll
  for (int rt = 0; rt < 4; ++rt)
#pragma unroll
    for (int ks = 0; ks < 2; ++ks)
      qf[rt][ks] = *(const bf16x8*)(Qb + (size_t)(rt * 16 + lr) * 1024 + ks * 32 + lg * 8);

  f32x4 acc[4][4] = {};
  float mrow[4][4], lrow[4][4];
#pragma unroll
  for (int rt = 0; rt < 4; ++rt)
#pragma unroll
    for (int r = 0; r < 4; ++r) { mrow[rt][r] = -__builtin_inff(); lrow[rt][r] = 0.f; }

  for (int kt = 0; kt < 32; ++kt) {
    // ---- scores: S = Q K^T (pre-scaled) ----
    f32x4 sc[4][4] = {};
#pragma unroll
    for (int ks = 0; ks < 2; ++ks) {
      bf16x8 kf[4];
#pragma unroll
      for (int ct = 0; ct < 4; ++ct)
        kf[ct] = *(const bf16x8*)(Kb + (size_t)(kt * 64 + ct * 16 + lr) * 64 + ks * 32 + lg * 8);
#pragma unroll
      for (int rt = 0; rt < 4; ++rt)
#pragma unroll
        for (int ct = 0; ct < 4; ++ct)
          sc[rt][ct] = __builtin_amdgcn_mfma_f32_16x16x32_bf16(qf[rt][ks], kf[ct], sc[rt][ct], 0, 0, 0);
    }
    // ---- online softmax (wave-parallel; rows live in 16-lane groups) ----
#pragma unroll
    for (int rt = 0; rt < 4; ++rt) {
#pragma unroll
      for (int r = 0; r < 4; ++r) {
        float mx = fmaxf(fmaxf(sc[rt][0][r], sc[rt][1][r]), fmaxf(sc[rt][2][r], sc[rt][3][r]));
#pragma unroll
        for (int off = 1; off < 16; off <<= 1) mx = fmaxf(mx, __shfl_xor(mx, off, 64));
        float mn = fmaxf(mrow[rt][r], mx);
        float corr = __builtin_amdgcn_exp2f(mrow[rt][r] - mn);
        mrow[rt][r] = mn;
        float rs = 0.f;
#pragma unroll
        for (int ct = 0; ct < 4; ++ct) {
          float p = __builtin_amdgcn_exp2f(sc[rt][ct][r] - mn);
          sc[rt][ct][r] = p;
          rs += p;
        }
#pragma unroll
        for (int off = 1; off < 16; off <<= 1) rs += __shfl_xor(rs, off, 64);
        lrow[rt][r] = lrow[rt][r] * corr + rs;
#pragma unroll
        for (int ct = 0; ct < 4; ++ct) acc[rt][ct][r] *= corr;
        // P -> LDS (bf16, XOR-swizzled rows; D-frag layout -> A-frag layout transpose)
        int row = rt * 16 + lg * 4 + r;
        int sw = (row & 7) << 3;
#pragma unroll
        for (int ct = 0; ct < 4; ++ct)
          P[row * 64 + ((ct * 16 + lr) ^ sw)] = bfbits(sc[rt][ct][r]);
      }
    }
    // ---- PV: acc += P * V^T  (V read from L2 as [d][keys]) ----
#pragma unroll
    for (int ks = 0; ks < 2; ++ks) {
      bf16x8 pf[4], vf[4];
#pragma unroll
      for (int rt = 0; rt < 4; ++rt) {
        int row = rt * 16 + lr;
        pf[rt] = *(const bf16x8*)&P[row * 64 + ((ks * 32 + lg * 8) ^ ((row & 7) << 3))];
      }
#pragma unroll
      for (int ct = 0; ct < 4; ++ct)
        vf[ct] = *(const bf16x8*)(Vb + (size_t)(ct * 16 + lr) * 2048 + kt * 64 + ks * 32 + lg * 8);
#pragma unroll
      for (int rt = 0; rt < 4; ++rt)
#pragma unroll
        for (int ct = 0; ct < 4; ++ct)
          acc[rt][ct] = __builtin_amdgcn_mfma_f32_16x16x32_bf16(pf[rt], vf[ct], acc[rt][ct], 0, 0, 0);
    }
  }
  // ---- epilogue: O / l -> att[b][s][h*64+d] bf16 ----
  u16* Ob = att + (size_t)(b * 2048 + q0) * 1024 + h * 64;
#pragma unroll
  for (int rt = 0; rt < 4; ++rt) {
#pragma unroll
    for (int r = 0; r < 4; ++r) {
      float inv = __builtin_amdgcn_rcpf(lrow[rt][r]);
      int row = rt * 16 + lg * 4 + r;
#pragma unroll
      for (int ct = 0; ct < 4; ++ct)
        Ob[(size_t)row * 1024 + ct * 16 + lr] = bfbits(acc[rt][ct][r] * inv);
    }
  }
}

// ---------------- launch ----------------
extern "C" void kernel_launch(void* const* d_in, const int* in_sizes, int n_in,
                              void* d_out, int out_size, void* d_ws, size_t ws_size,
                              hipStream_t stream) {
  const float* q  = (const float*)d_in[0];
  const float* k  = (const float*)d_in[1];
  const float* v  = (const float*)d_in[2];
  const float* Wq = (const float*)d_in[3];
  const float* bq = (const float*)d_in[4];
  const float* Wk = (const float*)d_in[5];
  const float* bk = (const float*)d_in[6];
  const float* Wv = (const float*)d_in[7];
  const float* bv = (const float*)d_in[8];
  const float* Wo = (const float*)d_in[9];
  const float* bo = (const float*)d_in[10];
  float* out = (float*)d_out;

  char* ws = (char*)d_ws;
  // workspace layout (bytes)
  u16* WqT = (u16*)(ws + 0);            // 1024*1024*2 = 2,097,152
  u16* WoT = (u16*)(ws + 2097152);      // 2,097,152
  u16* WkT = (u16*)(ws + 4194304);      // 131,072
  u16* WvT = (u16*)(ws + 4325376);      // 131,072
  u16* khb = (u16*)(ws + 4456448);      // 8192*64*2 = 1,048,576
  u16* vhT = (u16*)(ws + 5505024);      // 1,048,576
  u16* qhb = (u16*)(ws + 6553600);      // 8192*1024*2 = 16,777,216
  u16* cb0 = (u16*)(ws + 23330816);     // 16,777,216
  u16* cb1 = (u16*)(ws + 40108032);     // 16,777,216 (vb, then reused as att)

  // weight transposes (f32 -> bf16 [N][K])
  wtrans<<<dim3(32, 32), 256, 0, stream>>>(Wq, WqT, 1024, 1024);
  wtrans<<<dim3(32, 2),  256, 0, stream>>>(Wk, WkT, 1024, 64);
  wtrans<<<dim3(32, 2),  256, 0, stream>>>(Wv, WvT, 1024, 64);
  wtrans<<<dim3(32, 32), 256, 0, stream>>>(Wo, WoT, 1024, 1024);

  // Q projection (qh pre-scaled by 1/sqrt(dk)*log2e)
  cvt_f32_bf16<<<2048, 256, 0, stream>>>(q, cb0, 2097152);
  gemm_bt<128, 128, 2, 2, 2><<<dim3(8, 64), 256, 0, stream>>>(cb0, WqT, bq, (void*)qhb, 8192, 1024, 1024);

  // K projection
  cvt_f32_bf16<<<2048, 256, 0, stream>>>(k, cb0, 2097152);
  gemm_bt<128, 64, 4, 1, 1><<<dim3(1, 64), 256, 0, stream>>>(cb0, WkT, bk, (void*)khb, 8192, 64, 1024);

  // V projection (output transposed per-batch [b][d][s])
  cvt_f32_bf16<<<2048, 256, 0, stream>>>(v, cb1, 2097152);
  gemm_bt<128, 64, 4, 1, 3><<<dim3(1, 64), 256, 0, stream>>>(cb1, WvT, bv, (void*)vhT, 8192, 64, 1024);

  // fused attention -> att (reuses cb1)
  attn<<<dim3(8, 16, 4), 256, 0, stream>>>(qhb, khb, vhT, cb1);

  // O projection -> f32 out
  gemm_bt<128, 128, 2, 2, 0><<<dim3(8, 64), 256, 0, stream>>>(cb1, WoT, bo, (void*)out, 8192, 1024, 1024);
}

// Round 2
// 411.855 us; speedup vs baseline: 1.5110x; 1.5110x over previous
//
#include <hip/hip_runtime.h>
#include <hip/hip_bf16.h>

typedef unsigned short u16;
typedef float f32x4 __attribute__((ext_vector_type(4)));
typedef __bf16 bf16x8 __attribute__((ext_vector_type(8)));

#define DEVI static __device__ __forceinline__

static constexpr float QK_SCALE = 0.125f * 1.44269504088896340736f; // 1/sqrt(64) * log2(e)

DEVI u16 bfbits(float f) { __bf16 h = (__bf16)f; return __builtin_bit_cast(u16, h); }

typedef unsigned int uint_g __attribute__((address_space(1)));
typedef unsigned int uint_l __attribute__((address_space(3)));

DEVI void gl_lds16(const void* g, void* l) {
  __builtin_amdgcn_global_load_lds((const uint_g*)g, (uint_l*)l, 16, 0, 0);
}

// ---------------- f32 -> bf16 convert (vectorized) ----------------
__global__ __launch_bounds__(256) void cvt_f32_bf16(const float* __restrict__ x,
                                                    u16* __restrict__ y, int n4) {
  int i = blockIdx.x * blockDim.x + threadIdx.x;
  int stride = gridDim.x * blockDim.x;
  for (; i < n4; i += stride) {
    float4 v = ((const float4*)x)[i];
    ushort4 o;
    o.x = bfbits(v.x); o.y = bfbits(v.y); o.z = bfbits(v.z); o.w = bfbits(v.w);
    ((ushort4*)y)[i] = o;
  }
}

// ---------------- weight transpose W[K][N] f32 -> WT[N][K] bf16 ----------------
__global__ __launch_bounds__(256) void wtrans(const float* __restrict__ W,
                                              u16* __restrict__ WT, int K, int N) {
  __shared__ float t[32][33];
  int k0 = blockIdx.x * 32, n0 = blockIdx.y * 32;
  int tx = threadIdx.x & 31, ty = threadIdx.x >> 5;
#pragma unroll
  for (int i = 0; i < 4; ++i)
    t[ty + i * 8][tx] = W[(size_t)(k0 + ty + i * 8) * N + n0 + tx];
  __syncthreads();
#pragma unroll
  for (int i = 0; i < 4; ++i)
    WT[(size_t)(n0 + ty + i * 8) * K + k0 + tx] = bfbits(t[tx][ty + i * 8]);
}

// ---------------- bf16 GEMM: C[M,N] = A[M,K] * BT[N,K]^T + bias ----------------
// EPI: 0 = f32 out; 1 = bf16 out; 2 = bf16 out * QK_SCALE; 3 = bf16 out transposed per-batch [b][n][s]
template <int BM, int BN, int WM, int WN, int EPI>
__global__ __launch_bounds__(256) void gemm_bt(const u16* __restrict__ A,
                                               const u16* __restrict__ BT,
                                               const float* __restrict__ bias,
                                               void* __restrict__ out,
                                               int M, int N, int K) {
  constexpr int WROWS = BM / WM, WCOLS = BN / WN;
  constexpr int RT = WROWS / 16, CT = WCOLS / 16;
  __shared__ u16 Alds[BM * 64];
  __shared__ u16 Blds[BN * 64];
  const int tid = threadIdx.x, wave = tid >> 6, lane = tid & 63;
  const int lr = lane & 15, lg = lane >> 4;
  const int wr = wave / WN, wc = wave % WN;
  const int m0 = blockIdx.y * BM, n0 = blockIdx.x * BN;

  f32x4 acc[RT][CT] = {};
  const int nkt = K >> 6;
  for (int kt = 0; kt < nkt; ++kt) {
    const int k0 = kt * 64;
    // stage A tile [BM][64] with inverse-swizzled source so swizzled reads are linear
#pragma unroll
    for (int j = 0; j < BM / 32; ++j) {
      int row = j * 32 + (tid >> 3);
      int cel = ((tid & 7) * 8) ^ ((row & 7) << 3);
      gl_lds16(A + (size_t)(m0 + row) * K + k0 + cel,
               (char*)Alds + (j * 256 + wave * 64) * 16);
    }
#pragma unroll
    for (int j = 0; j < BN / 32; ++j) {
      int row = j * 32 + (tid >> 3);
      int cel = ((tid & 7) * 8) ^ ((row & 7) << 3);
      gl_lds16(BT + (size_t)(n0 + row) * K + k0 + cel,
               (char*)Blds + (j * 256 + wave * 64) * 16);
    }
    __syncthreads();
#pragma unroll
    for (int ks = 0; ks < 2; ++ks) {
      bf16x8 af[RT], bfv[CT];
#pragma unroll
      for (int rt = 0; rt < RT; ++rt) {
        int r = wr * WROWS + rt * 16 + lr;
        af[rt] = *(const bf16x8*)&Alds[r * 64 + ((ks * 32 + lg * 8) ^ ((r & 7) << 3))];
      }
#pragma unroll
      for (int ct = 0; ct < CT; ++ct) {
        int r = wc * WCOLS + ct * 16 + lr;
        bfv[ct] = *(const bf16x8*)&Blds[r * 64 + ((ks * 32 + lg * 8) ^ ((r & 7) << 3))];
      }
#pragma unroll
      for (int rt = 0; rt < RT; ++rt)
#pragma unroll
        for (int ct = 0; ct < CT; ++ct)
          acc[rt][ct] = __builtin_amdgcn_mfma_f32_16x16x32_bf16(af[rt], bfv[ct], acc[rt][ct], 0, 0, 0);
    }
    __syncthreads();
  }
  // epilogue
#pragma unroll
  for (int ct = 0; ct < CT; ++ct) {
    int n = n0 + wc * WCOLS + ct * 16 + lr;
    float bv = bias[n];
#pragma unroll
    for (int rt = 0; rt < RT; ++rt) {
#pragma unroll
      for (int r = 0; r < 4; ++r) {
        int m = m0 + wr * WROWS + rt * 16 + lg * 4 + r;
        float v = acc[rt][ct][r] + bv;
        if constexpr (EPI == 0) {
          ((float*)out)[(size_t)m * N + n] = v;
        } else if constexpr (EPI == 1) {
          ((u16*)out)[(size_t)m * N + n] = bfbits(v);
        } else if constexpr (EPI == 2) {
          ((u16*)out)[(size_t)m * N + n] = bfbits(v * QK_SCALE);
        } else {  // transposed per-batch: [b][n][s], S=2048
          int bb = m >> 11, s2 = m & 2047;
          ((u16*)out)[((size_t)bb * 64 + n) * 2048 + s2] = bfbits(v);
        }
      }
    }
  }
}

// ---------------- fused MQA attention (transposed-score form) ----------------
// grid (S/256, H, B), block 256 (4 waves, 64 q-rows each)
// qh [B*S][1024] bf16 (pre-scaled by QK_SCALE), kh [B*S][64] bf16, vhT [B][64][S] bf16
// ST = mfma(K, Q): D[k, q], q = lane&15 -> softmax is lane-local per q-row.
// O^T = mfma(V^T, P): D[d, q], q = lane&15 -> rescale is lane-local.
__global__ __launch_bounds__(256, 2) void attn(const u16* __restrict__ qh,
                                               const u16* __restrict__ kh,
                                               const u16* __restrict__ vhT,
                                               u16* __restrict__ att) {
  const int b = blockIdx.z, h = blockIdx.y;
  const int wave = threadIdx.x >> 6, lane = threadIdx.x & 63;
  const int lr = lane & 15, lg = lane >> 4;
  const int q0 = blockIdx.x * 256 + wave * 64;
  __shared__ u16 plds[4][64 * 64];
  char* P = (char*)plds[wave];  // [64 rows q][128 B], 16B-granule XOR swizzle
  const u16* Qb = qh + (size_t)(b * 2048 + q0) * 1024 + h * 64;
  const u16* Kb = kh + (size_t)b * 2048 * 64;
  const u16* Vb = vhT + (size_t)b * 64 * 2048;

  // Q as B-fragments: qf[rt][ks]: row q = rt*16+lr, k(d) = ks*32+lg*8
  bf16x8 qf[4][2];
#pragma unroll
  for (int rt = 0; rt < 4; ++rt)
#pragma unroll
    for (int ks = 0; ks < 2; ++ks)
      qf[rt][ks] = *(const bf16x8*)(Qb + (size_t)(rt * 16 + lr) * 1024 + ks * 32 + lg * 8);

  f32x4 acc[4][4] = {};          // [dt][rt]: d = dt*16+lg*4+r, q = rt*16+lr
  float mrow[4], lrow[4];        // per q = rt*16+lr (lane-local)
#pragma unroll
  for (int rt = 0; rt < 4; ++rt) { mrow[rt] = -__builtin_inff(); lrow[rt] = 0.f; }

  bf16x8 kA[4][2], kB[4][2];
  // preload K frags for kt=0: A-frag rows = keys
#pragma unroll
  for (int ct = 0; ct < 4; ++ct)
#pragma unroll
    for (int ks = 0; ks < 2; ++ks)
      kA[ct][ks] = *(const bf16x8*)(Kb + (size_t)(ct * 16 + lr) * 64 + ks * 32 + lg * 8);

  auto step = [&](int kt, bf16x8 (&kc)[4][2], bf16x8 (&kn)[4][2]) {
    // V^T A-frags for this kt (consumed after softmax -> natural prefetch)
    bf16x8 vf[4][2];
#pragma unroll
    for (int dt = 0; dt < 4; ++dt)
#pragma unroll
      for (int ks = 0; ks < 2; ++ks)
        vf[dt][ks] = *(const bf16x8*)(Vb + (size_t)(dt * 16 + lr) * 2048 + kt * 64 + ks * 32 + lg * 8);
    // ST = K Q^T : sc[ct][rt], k = ct*16+lg*4+r, q = rt*16+lr
    f32x4 sc[4][4] = {};
#pragma unroll
    for (int ks = 0; ks < 2; ++ks)
#pragma unroll
      for (int ct = 0; ct < 4; ++ct)
#pragma unroll
        for (int rt = 0; rt < 4; ++rt)
          sc[ct][rt] = __builtin_amdgcn_mfma_f32_16x16x32_bf16(kc[ct][ks], qf[rt][ks], sc[ct][rt], 0, 0, 0);
    // prefetch K frags for kt+1 (covered by softmax+PV latency)
    const int ktn = (kt + 1 < 32) ? kt + 1 : 31;
#pragma unroll
    for (int ct = 0; ct < 4; ++ct)
#pragma unroll
      for (int ks = 0; ks < 2; ++ks)
        kn[ct][ks] = *(const bf16x8*)(Kb + (size_t)(ktn * 64 + ct * 16 + lr) * 64 + ks * 32 + lg * 8);
    // ---- online softmax: fully lane-local per q = rt*16+lr ----
#pragma unroll
    for (int rt = 0; rt < 4; ++rt) {
      // in-register max tree over 16 values
      float m0 = fmaxf(fmaxf(sc[0][rt][0], sc[1][rt][0]), fmaxf(sc[2][rt][0], sc[3][rt][0]));
      float m1 = fmaxf(fmaxf(sc[0][rt][1], sc[1][rt][1]), fmaxf(sc[2][rt][1], sc[3][rt][1]));
      float m2 = fmaxf(fmaxf(sc[0][rt][2], sc[1][rt][2]), fmaxf(sc[2][rt][2], sc[3][rt][2]));
      float m3 = fmaxf(fmaxf(sc[0][rt][3], sc[1][rt][3]), fmaxf(sc[2][rt][3], sc[3][rt][3]));
      float mx = fmaxf(fmaxf(m0, m1), fmaxf(m2, m3));
      mx = fmaxf(mx, __shfl_xor(mx, 16, 64));
      mx = fmaxf(mx, __shfl_xor(mx, 32, 64));
      float mn = fmaxf(mrow[rt], mx);
      float corr = __builtin_amdgcn_exp2f(mrow[rt] - mn);
      mrow[rt] = mn;
      // exp + in-register sum tree
      f32x4 ps = {};
#pragma unroll
      for (int ct = 0; ct < 4; ++ct) {
#pragma unroll
        for (int r = 0; r < 4; ++r)
          sc[ct][rt][r] = __builtin_amdgcn_exp2f(sc[ct][rt][r] - mn);
        ps += sc[ct][rt];
      }
      float rs = (ps[0] + ps[1]) + (ps[2] + ps[3]);
      rs += __shfl_xor(rs, 16, 64);
      rs += __shfl_xor(rs, 32, 64);
      lrow[rt] = lrow[rt] * corr + rs;
#pragma unroll
      for (int dt = 0; dt < 4; ++dt) acc[dt][rt] *= corr;
      // P -> LDS row q, packed b64 writes, swizzled
      const int row = rt * 16 + lr;
      const int sw = (row & 7) << 4;
#pragma unroll
      for (int ct = 0; ct < 4; ++ct) {
        ushort4 pk;
        pk.x = bfbits(sc[ct][rt][0]); pk.y = bfbits(sc[ct][rt][1]);
        pk.z = bfbits(sc[ct][rt][2]); pk.w = bfbits(sc[ct][rt][3]);
        *(ushort4*)(P + row * 128 + ((ct * 32 + lg * 8) ^ sw)) = pk;
      }
    }
    // ---- PV: acc[d][q] += V^T[d][k] * P[q][k] ----
#pragma unroll
    for (int ks = 0; ks < 2; ++ks) {
      bf16x8 pf[4];
#pragma unroll
      for (int rt = 0; rt < 4; ++rt) {
        const int row = rt * 16 + lr;
        pf[rt] = *(const bf16x8*)(P + row * 128 + ((ks * 64 + lg * 16) ^ ((row & 7) << 4)));
      }
#pragma unroll
      for (int dt = 0; dt < 4; ++dt)
#pragma unroll
        for (int rt = 0; rt < 4; ++rt)
          acc[dt][rt] = __builtin_amdgcn_mfma_f32_16x16x32_bf16(vf[dt][ks], pf[rt], acc[dt][rt], 0, 0, 0);
    }
  };

#pragma unroll 1
  for (int kt2 = 0; kt2 < 16; ++kt2) {
    step(2 * kt2, kA, kB);
    step(2 * kt2 + 1, kB, kA);
  }

  // ---- epilogue: O^T -> LDS transpose -> coalesced bf16 stores ----
#pragma unroll
  for (int rt = 0; rt < 4; ++rt) {
    float inv = __builtin_amdgcn_rcpf(lrow[rt]);
    const int row = rt * 16 + lr;
    const int sw = (row & 7) << 4;
#pragma unroll
    for (int dt = 0; dt < 4; ++dt) {
      ushort4 ok;
      ok.x = bfbits(acc[dt][rt][0] * inv); ok.y = bfbits(acc[dt][rt][1] * inv);
      ok.z = bfbits(acc[dt][rt][2] * inv); ok.w = bfbits(acc[dt][rt][3] * inv);
      *(ushort4*)(P + row * 128 + ((dt * 32 + lg * 8) ^ sw)) = ok;
    }
  }
  u16* Ob = att + (size_t)(b * 2048 + q0) * 1024 + h * 64;
#pragma unroll
  for (int it = 0; it < 8; ++it) {
    const int row = it * 8 + (lane >> 3);
    const int g = lane & 7;
    uint4 vv = *(const uint4*)(P + row * 128 + ((g * 16) ^ ((row & 7) << 4)));
    *(uint4*)(Ob + (size_t)row * 1024 + g * 8) = vv;
  }
}

// ---------------- launch ----------------
extern "C" void kernel_launch(void* const* d_in, const int* in_sizes, int n_in,
                              void* d_out, int out_size, void* d_ws, size_t ws_size,
                              hipStream_t stream) {
  const float* q  = (const float*)d_in[0];
  const float* k  = (const float*)d_in[1];
  const float* v  = (const float*)d_in[2];
  const float* Wq = (const float*)d_in[3];
  const float* bq = (const float*)d_in[4];
  const float* Wk = (const float*)d_in[5];
  const float* bk = (const float*)d_in[6];
  const float* Wv = (const float*)d_in[7];
  const float* bv = (const float*)d_in[8];
  const float* Wo = (const float*)d_in[9];
  const float* bo = (const float*)d_in[10];
  float* out = (float*)d_out;

  char* ws = (char*)d_ws;
  // workspace layout (bytes)
  u16* WqT = (u16*)(ws + 0);            // 2,097,152
  u16* WoT = (u16*)(ws + 2097152);      // 2,097,152
  u16* WkT = (u16*)(ws + 4194304);      // 131,072
  u16* WvT = (u16*)(ws + 4325376);      // 131,072
  u16* khb = (u16*)(ws + 4456448);      // 1,048,576
  u16* vhT = (u16*)(ws + 5505024);      // 1,048,576
  u16* qhb = (u16*)(ws + 6553600);      // 16,777,216
  u16* cb0 = (u16*)(ws + 23330816);     // 16,777,216
  u16* cb1 = (u16*)(ws + 40108032);     // 16,777,216 (v bf16, then reused as att)

  // weight transposes (f32 -> bf16 [N][K])
  wtrans<<<dim3(32, 32), 256, 0, stream>>>(Wq, WqT, 1024, 1024);
  wtrans<<<dim3(32, 2),  256, 0, stream>>>(Wk, WkT, 1024, 64);
  wtrans<<<dim3(32, 2),  256, 0, stream>>>(Wv, WvT, 1024, 64);
  wtrans<<<dim3(32, 32), 256, 0, stream>>>(Wo, WoT, 1024, 1024);

  // Q projection (qh pre-scaled by 1/sqrt(dk)*log2e)
  cvt_f32_bf16<<<2048, 256, 0, stream>>>(q, cb0, 2097152);
  gemm_bt<128, 128, 2, 2, 2><<<dim3(8, 64), 256, 0, stream>>>(cb0, WqT, bq, (void*)qhb, 8192, 1024, 1024);

  // K projection
  cvt_f32_bf16<<<2048, 256, 0, stream>>>(k, cb0, 2097152);
  gemm_bt<64, 64, 2, 2, 1><<<dim3(1, 128), 256, 0, stream>>>(cb0, WkT, bk, (void*)khb, 8192, 64, 1024);

  // V projection (output transposed per-batch [b][d][s])
  cvt_f32_bf16<<<2048, 256, 0, stream>>>(v, cb1, 2097152);
  gemm_bt<64, 64, 2, 2, 3><<<dim3(1, 128), 256, 0, stream>>>(cb1, WvT, bv, (void*)vhT, 8192, 64, 1024);

  // fused attention -> att (reuses cb1)
  attn<<<dim3(8, 16, 4), 256, 0, stream>>>(qhb, khb, vhT, cb1);

  // O projection -> f32 out
  gemm_bt<128, 128, 2, 2, 0><<<dim3(8, 64), 256, 0, stream>>>(cb1, WoT, bo, (void*)out, 8192, 1024, 1024);
}